// Round 4
// baseline (443.943 us; speedup 1.0000x reference)
//
#include <hip/hip_runtime.h>

// Problem constants
#define Bn 256
#define Vn 512
#define Fn 256
// O = 2 hard-coded throughout.

// Workspace layout (bytes):
//   packed adjacency bits: [Bn*Vn][8] uint64  at 0        (8 MB)
//   dinv:                  [Bn*Vn] float      at 8388608   (512 KB)
//   Ypre = (X@W)*dinv:     [Bn*Vn] float2     at 8912896   (1 MB)
#define WS_PACKED_OFF 0
#define WS_DINV_OFF   8388608
#define WS_Y_OFF      8912896

// Fused pack + degree + X@W kernel: one wave per TWO rows (r0 = 2*wid, r0+1).
// 8 VMEM loads (6 KB) issued up front for MLP; 16 ballots + 4 independent
// shfl-reduce chains pipeline the cross-lane latency.  Bit packing uses a
// PERMUTED order: word j = q*4+c (q in {0,1}, c in {0..3}), bit L of word j
// <-> element 256q + 4L + c.  Degree (popcount) is order-invariant; the
// aggregation kernel unpacks in the same order.  Y is written PRE-MULTIPLIED
// by dinv (column norm folded here).
__global__ __launch_bounds__(256) void fused_pack_xw_kernel(
    const int* __restrict__ G,
    const float* __restrict__ X,
    const float* __restrict__ W,
    unsigned long long* __restrict__ P,
    float* __restrict__ dinv,
    float2* __restrict__ Y) {
  int gid  = blockIdx.x * 256 + threadIdx.x;
  int wid  = gid >> 6;
  int lane = gid & 63;
  int row0 = wid << 1;            // wave-uniform; row1 = row0 + 1
  int v0   = row0 & (Vn - 1);     // even -> v1 = v0 + 1 (same batch)
  int v1   = v0 + 1;

  // ---- issue ALL global loads up front (2 graph rows + 2 feature rows) ----
  const int4* gA = (const int4*)(G + (size_t)row0 * Vn);
  const int4* gB = (const int4*)(G + ((size_t)row0 + 1) * Vn);
  int4 A0 = gA[lane];             // row0 elements 4L .. 4L+3
  int4 A1 = gA[64 + lane];        // row0 elements 256+4L .. 256+4L+3
  int4 B0 = gB[lane];
  int4 B1 = gB[64 + lane];

  const float4* xrA = (const float4*)(X + (size_t)row0 * Fn);
  const float4* xrB = (const float4*)(X + ((size_t)row0 + 1) * Fn);
  float4 xA = xrA[lane];
  float4 xB = xrB[lane];
  const float4* wr = (const float4*)W;   // W is [F,2] row-major, L1-resident
  float4 w0 = wr[lane * 2];       // {W[4L][0],W[4L][1],W[4L+1][0],W[4L+1][1]}
  float4 w1 = wr[lane * 2 + 1];   // {W[4L+2][0],W[4L+2][1],W[4L+3][0],W[4L+3][1]}

  // ---- permuted ballots (results are wave-uniform / scalar) ----
  unsigned long long a0 = __ballot(A0.x != 0);
  unsigned long long a1 = __ballot(A0.y != 0);
  unsigned long long a2 = __ballot(A0.z != 0);
  unsigned long long a3 = __ballot(A0.w != 0);
  unsigned long long a4 = __ballot(A1.x != 0);
  unsigned long long a5 = __ballot(A1.y != 0);
  unsigned long long a6 = __ballot(A1.z != 0);
  unsigned long long a7 = __ballot(A1.w != 0);
  unsigned long long b0 = __ballot(B0.x != 0);
  unsigned long long b1 = __ballot(B0.y != 0);
  unsigned long long b2 = __ballot(B0.z != 0);
  unsigned long long b3 = __ballot(B0.w != 0);
  unsigned long long b4 = __ballot(B1.x != 0);
  unsigned long long b5 = __ballot(B1.y != 0);
  unsigned long long b6 = __ballot(B1.z != 0);
  unsigned long long b7 = __ballot(B1.w != 0);

  // Self-loop bits: element v -> word ((v>>8)<<2)|(v&3), bit (v>>2)&63.
  // All wave-uniform -> scalar branch chains.
  {
    int wA = ((v0 >> 8) << 2) | (v0 & 3);
    unsigned long long dbA = 1ull << ((v0 >> 2) & 63);
    if      (wA == 0) a0 |= dbA;
    else if (wA == 1) a1 |= dbA;
    else if (wA == 2) a2 |= dbA;
    else if (wA == 3) a3 |= dbA;
    else if (wA == 4) a4 |= dbA;
    else if (wA == 5) a5 |= dbA;
    else if (wA == 6) a6 |= dbA;
    else              a7 |= dbA;
    int wB = ((v1 >> 8) << 2) | (v1 & 3);
    unsigned long long dbB = 1ull << ((v1 >> 2) & 63);
    if      (wB == 0) b0 |= dbB;
    else if (wB == 1) b1 |= dbB;
    else if (wB == 2) b2 |= dbB;
    else if (wB == 3) b3 |= dbB;
    else if (wB == 4) b4 |= dbB;
    else if (wB == 5) b5 |= dbB;
    else if (wB == 6) b6 |= dbB;
    else              b7 |= dbB;
  }

  int degA = __popcll(a0) + __popcll(a1) + __popcll(a2) + __popcll(a3) +
             __popcll(a4) + __popcll(a5) + __popcll(a6) + __popcll(a7);
  int degB = __popcll(b0) + __popcll(b1) + __popcll(b2) + __popcll(b3) +
             __popcll(b4) + __popcll(b5) + __popcll(b6) + __popcll(b7);

  // ---- X @ W (O=2) for both rows: 4 independent reduce chains ----
  float s0A = xA.x * w0.x + xA.y * w0.z + xA.z * w1.x + xA.w * w1.z;
  float s1A = xA.x * w0.y + xA.y * w0.w + xA.z * w1.y + xA.w * w1.w;
  float s0B = xB.x * w0.x + xB.y * w0.z + xB.z * w1.x + xB.w * w1.z;
  float s1B = xB.x * w0.y + xB.y * w0.w + xB.z * w1.y + xB.w * w1.w;
  #pragma unroll
  for (int off = 32; off; off >>= 1) {
    s0A += __shfl_xor(s0A, off);
    s1A += __shfl_xor(s1A, off);
    s0B += __shfl_xor(s0B, off);
    s1B += __shfl_xor(s1B, off);
  }

  // Lanes 0..7 store row0's words, lanes 8..15 store row1's words:
  // P index (size_t)row0*8 + lane is correct for both (row1*8 = row0*8+8).
  unsigned long long sel = a0;
  sel = (lane ==  1) ? a1 : sel;
  sel = (lane ==  2) ? a2 : sel;
  sel = (lane ==  3) ? a3 : sel;
  sel = (lane ==  4) ? a4 : sel;
  sel = (lane ==  5) ? a5 : sel;
  sel = (lane ==  6) ? a6 : sel;
  sel = (lane ==  7) ? a7 : sel;
  sel = (lane ==  8) ? b0 : sel;
  sel = (lane ==  9) ? b1 : sel;
  sel = (lane == 10) ? b2 : sel;
  sel = (lane == 11) ? b3 : sel;
  sel = (lane == 12) ? b4 : sel;
  sel = (lane == 13) ? b5 : sel;
  sel = (lane == 14) ? b6 : sel;
  sel = (lane == 15) ? b7 : sel;
  if (lane < 16) P[(size_t)row0 * 8 + lane] = sel;

  // Lanes 0..1 store dinv and premultiplied Y for rows row0, row0+1.
  if (lane < 2) {
    float d  = rsqrtf((float)(lane ? degB : degA));
    float s0 = lane ? s0B : s0A;
    float s1 = lane ? s1B : s1A;
    dinv[row0 + lane] = d;
    Y[row0 + lane] = make_float2(s0 * d, s1 * d);
  }
}

// Aggregation + bias + relu + head dot + sigmoid.  One block of 512 threads
// per batch element.  Thread t owns row v = t.  LDS holds Ypre[b,w,:]
// (already * dinv[w]); bit k of word j = q*4+c maps to element 256q+4k+c,
// so elements 4k..4k+3 are CONSECUTIVE -> two uniform ds_read_b128 serve
// 4 bits.  8 independent accumulator chains (4 per channel) for ILP.
__global__ __launch_bounds__(512) void agg_head_kernel(
    const unsigned long long* __restrict__ P,
    const float* __restrict__ dinv,
    const float2* __restrict__ Y,
    const float* __restrict__ lw,
    const float* __restrict__ lb,
    const float* __restrict__ cb,
    float* __restrict__ out) {
  __shared__ float2 ylds[Vn];
  __shared__ float wsum[8];

  int b = blockIdx.x;
  int t = threadIdx.x;          // = row v

  // Issue this row's 64 B of mask words FIRST (hide HBM latency under
  // staging + barrier).
  const ulonglong2* p2 = (const ulonglong2*)(P + ((size_t)b * Vn + t) * 8);
  ulonglong2 q0 = p2[0];        // words 0,1  (q=0, c=0,1)
  ulonglong2 q1 = p2[1];        // words 2,3  (q=0, c=2,3)
  ulonglong2 q2 = p2[2];        // words 4,5  (q=1, c=0,1)
  ulonglong2 q3 = p2[3];        // words 6,7  (q=1, c=2,3)

  float d = dinv[b * Vn + t];
  ylds[t] = Y[b * Vn + t];      // pure copy (dinv already folded)
  __syncthreads();

  const float4* y4 = (const float4*)ylds;   // y4[i] = elements {2i, 2i+1}

  // 8 independent accumulator chains: a{c}{chan}, c = word-c (0..3).
  float a0x = 0.f, a0y = 0.f, a1x = 0.f, a1y = 0.f;
  float a2x = 0.f, a2y = 0.f, a3x = 0.f, a3y = 0.f;

  #pragma unroll
  for (int q = 0; q < 2; ++q) {
    unsigned long long w0 = q ? q2.x : q0.x;   // c=0
    unsigned long long w1 = q ? q2.y : q0.y;   // c=1
    unsigned long long w2 = q ? q3.x : q1.x;   // c=2
    unsigned long long w3 = q ? q3.y : q1.y;   // c=3
    #pragma unroll
    for (int half = 0; half < 2; ++half) {
      unsigned b0 = half ? (unsigned)(w0 >> 32) : (unsigned)w0;
      unsigned b1 = half ? (unsigned)(w1 >> 32) : (unsigned)w1;
      unsigned b2 = half ? (unsigned)(w2 >> 32) : (unsigned)w2;
      unsigned b3 = half ? (unsigned)(w3 >> 32) : (unsigned)w3;
      int ibase = 128 * q + 64 * half;         // float4 index of element 4k
      #pragma unroll
      for (int k = 0; k < 32; ++k) {
        float4 ya = y4[ibase + 2 * k];         // elems 4K, 4K+1 (uniform)
        float4 yb = y4[ibase + 2 * k + 1];     // elems 4K+2, 4K+3
        float s0 = (float)((b0 >> k) & 1u);
        float s1 = (float)((b1 >> k) & 1u);
        float s2 = (float)((b2 >> k) & 1u);
        float s3 = (float)((b3 >> k) & 1u);
        a0x = fmaf(s0, ya.x, a0x); a0y = fmaf(s0, ya.y, a0y);
        a1x = fmaf(s1, ya.z, a1x); a1y = fmaf(s1, ya.w, a1y);
        a2x = fmaf(s2, yb.x, a2x); a2y = fmaf(s2, yb.y, a2y);
        a3x = fmaf(s3, yb.z, a3x); a3y = fmaf(s3, yb.w, a3y);
      }
    }
  }
  float A0 = (a0x + a1x) + (a2x + a3x);
  float A1 = (a0y + a1y) + (a2y + a3y);

  float cb0 = cb[0], cb1 = cb[1];
  const float2* lw2 = (const float2*)lw;      // lw flat index = v*2 + o
  float2 wv = lw2[t];

  float h0 = fmaxf(fmaf(d, A0, cb0), 0.f);
  float h1 = fmaxf(fmaf(d, A1, cb1), 0.f);
  float c = h0 * wv.x + h1 * wv.y;

  #pragma unroll
  for (int off = 32; off; off >>= 1) c += __shfl_xor(c, off);
  if ((t & 63) == 0) wsum[t >> 6] = c;
  __syncthreads();
  if (t == 0) {
    float logit = wsum[0] + wsum[1] + wsum[2] + wsum[3] +
                  wsum[4] + wsum[5] + wsum[6] + wsum[7] + lb[0];
    out[b] = 1.0f / (1.0f + expf(-logit));
  }
}

extern "C" void kernel_launch(void* const* d_in, const int* in_sizes, int n_in,
                              void* d_out, int out_size, void* d_ws, size_t ws_size,
                              hipStream_t stream) {
  const float* features = (const float*)d_in[0];
  const int*   graphs   = (const int*)d_in[1];
  const float* conv_w   = (const float*)d_in[2];
  const float* conv_b   = (const float*)d_in[3];
  const float* lin_w    = (const float*)d_in[4];
  const float* lin_b    = (const float*)d_in[5];
  float* out = (float*)d_out;

  char* ws = (char*)d_ws;
  unsigned long long* P = (unsigned long long*)(ws + WS_PACKED_OFF);
  float*  dinv = (float*)(ws + WS_DINV_OFF);
  float2* Y    = (float2*)(ws + WS_Y_OFF);

  // Fused pack+deg+XW: 131072 rows, TWO rows per wave -> 16384 blocks of 256
  fused_pack_xw_kernel<<<dim3(16384), dim3(256), 0, stream>>>(
      graphs, features, conv_w, P, dinv, Y);
  // Aggregation + head: one block of 512 per batch element
  agg_head_kernel<<<dim3(Bn), dim3(512), 0, stream>>>(
      P, dinv, Y, lin_w, lin_b, conv_b, out);
}